// Round 16
// baseline (94.024 us; speedup 1.0000x reference)
//
#include <hip/hip_runtime.h>

#define COLS 16384
#define TPB  1024
#define NV   4                   // vec4 per thread per row (4*1024*4 = 16384)
#define NW   (TPB / 64)          // 16 waves
#define NBIN 4096
#define CHK  (NBIN / TPB)        // 4 bins per thread in the scan
#define SH1  12
#define RPB  2                   // rows per block (fused select)

typedef unsigned uvec4 __attribute__((ext_vector_type(4)));
typedef float    fvec4 __attribute__((ext_vector_type(4)));

__global__ __launch_bounds__(TPB, 8) void topk_abs_kernel(
    const float* __restrict__ x, const int* __restrict__ kp,
    float* __restrict__ out, int rows)
{
    __shared__ int      hist[2][NBIN];   // 32 KB: one 4096-bin hist per row
    __shared__ unsigned wsum2[NW];       // packed dual-scan partials
    __shared__ int      wsum[NW];        // fallback 256-bin scan partials
    __shared__ unsigned s_cnt, s_max;
    __shared__ unsigned s_total[2];
    __shared__ int      s_bin[2], s_G[2], s_eq[2];

    const int tid = threadIdx.x, lane = tid & 63, wid = tid >> 6;
    const int row0 = blockIdx.x * RPB;
    const int kin = kp[0];
    const unsigned kk = (unsigned)(kin < 0 ? 0 : (kin > COLS ? COLS : kin));

    const uvec4* __restrict__ xrA = (const uvec4*)(x + (size_t)row0 * COLS);
    const uvec4* __restrict__ xrB = (const uvec4*)(x + (size_t)(row0 + 1) * COLS);
    fvec4* __restrict__ orA = (fvec4*)(out + (size_t)row0 * COLS);
    fvec4* __restrict__ orB = (fvec4*)(out + (size_t)(row0 + 1) * COLS);
    const bool hasB = (row0 + 1) < rows;

    // ---- PLAIN cached loads (L3 serves ~50% across replays; NT loads forfeit
    // it — r12 vs r7 A/B). NT stores keep output stream from evicting input. ----
    uvec4 ubA[NV], ubB[NV];
    #pragma unroll
    for (int i = 0; i < NV; ++i) ubA[i] = xrA[i * TPB + tid];
    if (hasB) {
        #pragma unroll
        for (int i = 0; i < NV; ++i) ubB[i] = xrB[i * TPB + tid];
    }
    #pragma unroll
    for (int j = 0; j < CHK; ++j) { hist[0][tid + j * TPB] = 0; hist[1][tid + j * TPB] = 0; }
    __syncthreads();

    const unsigned T0 = 0x3FE66666u;     // bits(1.8f)

    // ---- Pass 1 (FUSED): |x| mask + fixed-bin hist for BOTH rows, one barrier.
    // Bins (u-T0)>>12 over |x| in [1.8,7.2); ~1180 counts/row for N(0,1). ----
    #pragma unroll
    for (int i = 0; i < NV; ++i) {
        uvec4 t = ubA[i] & 0x7FFFFFFFu; ubA[i] = t;
        #define H1(u) { if ((u) >= T0) { unsigned b = ((u) - T0) >> SH1; \
                        b = b < (NBIN - 1) ? b : (NBIN - 1); atomicAdd(&hist[0][b], 1); } }
        H1(t.x) H1(t.y) H1(t.z) H1(t.w)
        #undef H1
    }
    if (hasB) {
        #pragma unroll
        for (int i = 0; i < NV; ++i) {
            uvec4 t = ubB[i] & 0x7FFFFFFFu; ubB[i] = t;
            #define H1(u) { if ((u) >= T0) { unsigned b = ((u) - T0) >> SH1; \
                            b = b < (NBIN - 1) ? b : (NBIN - 1); atomicAdd(&hist[1][b], 1); } }
            H1(t.x) H1(t.y) H1(t.z) H1(t.w)
            #undef H1
        }
    }
    __syncthreads();

    // ---- Packed dual descending suffix-scan + crossing pick (both rows in
    // one shfl chain: row A in bits[0,16), row B in bits[16,32), sums<=16384
    // so no cross-half carry). ----
    auto scan2 = [&](int rankA, int rankB) {
        const int c  = (TPB - 1) - tid;          // tid 0 owns the TOP chunk
        const int b0 = c * CHK;
        unsigned SA = 0, SB = 0;
        #pragma unroll
        for (int j = 0; j < CHK; ++j) { SA += (unsigned)hist[0][b0 + j]; SB += (unsigned)hist[1][b0 + j]; }
        unsigned P = SA | (SB << 16);
        #pragma unroll
        for (int d = 1; d < 64; d <<= 1) { unsigned t = (unsigned)__shfl_up((int)P, d); if (lane >= d) P += t; }
        if (lane == 63) wsum2[wid] = P;
        __syncthreads();
        for (int w = 0; w < wid; ++w) P += wsum2[w];
        const int PA = (int)(P & 0xFFFFu), PB = (int)(P >> 16);
        if (PA >= rankA && PA - (int)SA < rankA) {       // unique crossing chunk, row A
            int cum = PA - (int)SA;
            #pragma unroll
            for (int j = CHK - 1; j >= 0; --j) {
                int h = hist[0][b0 + j], prev = cum; cum += h;
                if (cum >= rankA && prev < rankA) { s_bin[0] = b0 + j; s_G[0] = prev; s_eq[0] = h; }
            }
        }
        if (PB >= rankB && PB - (int)SB < rankB) {       // row B
            int cum = PB - (int)SB;
            #pragma unroll
            for (int j = CHK - 1; j >= 0; --j) {
                int h = hist[1][b0 + j], prev = cum; cum += h;
                if (cum >= rankB && prev < rankB) { s_bin[1] = b0 + j; s_G[1] = prev; s_eq[1] = h; }
            }
        }
        if (tid == TPB - 1) { s_total[0] = (unsigned)PA; s_total[1] = (unsigned)PB; }
        __syncthreads();
    };

    unsigned TA = 0xFFFFFFFFu, TB = 0xFFFFFFFFu;   // kk==0 -> accept nothing
    int needA = 0, eqA = 0, needB = 0, eqB = 0;
    bool p2A = false, p2B = false, fbA = false, fbB = false;
    unsigned A1A = 0, A1B = 0, cntA = 0, cntB = 0;
    int r1A = 1, r1B = 1;

    if (kk > 0) {
        scan2((int)kk, (int)kk);
        {
            cntA = s_total[0];
            const int B1 = s_bin[0], G1 = s_G[0], E1 = s_eq[0];
            if (cntA == kk) TA = T0;
            else if (cntA > kk && B1 < NBIN - 1) {
                if (G1 + E1 == (int)kk) TA = T0 + ((unsigned)B1 << SH1);   // whole bin accepted
                else { p2A = true; A1A = T0 + ((unsigned)B1 << SH1); r1A = (int)kk - G1; }
            } else fbA = true;
        }
        if (hasB) {
            cntB = s_total[1];
            const int B1 = s_bin[1], G1 = s_G[1], E1 = s_eq[1];
            if (cntB == kk) TB = T0;
            else if (cntB > kk && B1 < NBIN - 1) {
                if (G1 + E1 == (int)kk) TB = T0 + ((unsigned)B1 << SH1);
                else { p2B = true; A1B = T0 + ((unsigned)B1 << SH1); r1B = (int)kk - G1; }
            } else fbB = true;
        }

        // ---- Pass 2 (FUSED, ~25%/row): exact select inside the crossing bin
        // (window 4096 keys), shared barriers for whichever rows need it. ----
        if (p2A || p2B) {
            #pragma unroll
            for (int j = 0; j < CHK; ++j) { hist[0][tid + j * TPB] = 0; hist[1][tid + j * TPB] = 0; }
            __syncthreads();
            if (p2A) {
                #pragma unroll
                for (int i = 0; i < NV; ++i) {
                    #define H2(u) { unsigned d = (u) - A1A; if (d < (unsigned)NBIN) atomicAdd(&hist[0][d], 1); }
                    H2(ubA[i].x) H2(ubA[i].y) H2(ubA[i].z) H2(ubA[i].w)
                    #undef H2
                }
            }
            if (p2B) {
                #pragma unroll
                for (int i = 0; i < NV; ++i) {
                    #define H2(u) { unsigned d = (u) - A1B; if (d < (unsigned)NBIN) atomicAdd(&hist[1][d], 1); }
                    H2(ubB[i].x) H2(ubB[i].y) H2(ubB[i].z) H2(ubB[i].w)
                    #undef H2
                }
            }
            __syncthreads();
            scan2(p2A ? r1A : 1, p2B ? r1B : 1);   // empty hist never crosses rank 1
            if (p2A) { TA = A1A + (unsigned)s_bin[0]; needA = r1A - s_G[0]; eqA = s_eq[0]; }
            if (p2B) { TB = A1B + (unsigned)s_bin[1]; needB = r1B - s_G[1]; eqB = s_eq[1]; }
        }

        // ---- Rare fallback (cnt < kk, or boundary in clamp bin): bisection +
        // adaptive 256-bin radix from registers (uses hist[0][0..255]). ----
        auto fallback = [&](uvec4 (&ub)[NV], unsigned cnt0, unsigned &T, int &need, int &eq) {
            if (tid == 0) s_max = 0u;
            __syncthreads();
            unsigned lmax = 0u;
            #pragma unroll
            for (int i = 0; i < NV; ++i)
                lmax = max(lmax, max(max(ub[i].x, ub[i].y), max(ub[i].z, ub[i].w)));
            #pragma unroll
            for (int d = 32; d; d >>= 1) lmax = max(lmax, (unsigned)__shfl_xor((int)lmax, d));
            if (lane == 0) atomicMax(&s_max, lmax);
            __syncthreads();
            const unsigned smax = s_max;

            auto count_ge = [&](unsigned Tq) -> unsigned {
                __syncthreads();
                if (tid == 0) s_cnt = 0;
                __syncthreads();
                int c = 0;
                #pragma unroll
                for (int i = 0; i < NV; ++i)
                    c += (ub[i].x >= Tq) + (ub[i].y >= Tq) + (ub[i].z >= Tq) + (ub[i].w >= Tq);
                #pragma unroll
                for (int d = 32; d; d >>= 1) c += __shfl_xor(c, d);
                if (lane == 0) atomicAdd(&s_cnt, (unsigned)c);
                __syncthreads();
                return s_cnt;
            };

            unsigned T0f = T0, cntf = cnt0;
            if (cntf < kk) {
                unsigned lo = 0u, hi = T0;
                while (hi - lo > 1u) {
                    unsigned mid = lo + ((hi - lo) >> 1);
                    if (count_ge(mid) >= kk) lo = mid; else hi = mid;
                }
                T0f = lo;
                cntf = count_ge(T0f);
            }
            if (cntf == kk)       { T = T0f; need = 0; eq = 0; return; }
            if (smax == T0f)      { T = T0f; eq = (int)cntf; need = (int)kk; return; }
            const unsigned range = smax - T0f;
            const int topbit = 31 - __clz(range);
            int sh = topbit - 7; if (sh < 0) sh = 0;
            unsigned A = T0f;
            unsigned W = (topbit >= 31) ? 0xFFFFFFFFu : (1u << (topbit + 1));
            int r = (int)kk;
            for (;;) {
                if (tid < 256) hist[0][tid] = 0;
                __syncthreads();
                #pragma unroll
                for (int i = 0; i < NV; ++i) {
                    #define HR(u) { if ((u) >= A && ((u) - A) < W) atomicAdd(&hist[0][((u) - A) >> sh], 1); }
                    HR(ub[i].x) HR(ub[i].y) HR(ub[i].z) HR(ub[i].w)
                    #undef HR
                }
                __syncthreads();
                int bin = 0, val = 0, s = 0;
                if (tid < 256) {
                    bin = 255 - tid;
                    val = hist[0][bin];
                    s = val;
                    #pragma unroll
                    for (int d = 1; d < 64; d <<= 1) { int t = __shfl_up(s, d); if (lane >= d) s += t; }
                    if (lane == 63) wsum[wid] = s;
                }
                __syncthreads();
                if (tid < 256) {
                    for (int w = 0; w < wid; ++w) s += wsum[w];
                    if (s >= r && (s - val) < r) { s_bin[0] = bin; s_G[0] = s - val; if (sh == 0) s_eq[0] = val; }
                }
                __syncthreads();
                A += ((unsigned)s_bin[0]) << sh;
                W = 1u << sh;
                r -= s_G[0];
                if (sh == 0) break;
                sh = (sh >= 8) ? sh - 8 : 0;
                __syncthreads();
            }
            T = A; need = r; eq = s_eq[0];
        };
        if (fbA)          fallback(ubA, cntA, TA, needA, eqA);
        if (hasB && fbB)  fallback(ubB, cntB, TB, needB, eqB);
    }

    // ---- Boundary tie (need != eq, rare): among u==T accept the `need`
    // lowest columns; bisect cutoff column with register-direct counts. ----
    auto tie_cut = [&](uvec4 (&ub)[NV], unsigned T, int need) -> unsigned {
        unsigned loC = 0, hiC = COLS - 1;
        while (loC < hiC) {
            unsigned mid = (loC + hiC) >> 1;
            __syncthreads();
            if (tid == 0) s_cnt = 0;
            __syncthreads();
            int c = 0;
            #pragma unroll
            for (int i = 0; i < NV; ++i) {
                const unsigned cb = (unsigned)(i * TPB + tid) * 4u;
                c += (ub[i].x == T && (cb + 0) <= mid);
                c += (ub[i].y == T && (cb + 1) <= mid);
                c += (ub[i].z == T && (cb + 2) <= mid);
                c += (ub[i].w == T && (cb + 3) <= mid);
            }
            #pragma unroll
            for (int d = 32; d; d >>= 1) c += __shfl_xor(c, d);
            if (lane == 0) atomicAdd(&s_cnt, (unsigned)c);
            __syncthreads();
            if (s_cnt >= (unsigned)need) hiC = mid; else loC = mid + 1;
        }
        return loC;
    };
    unsigned cstarA = COLS - 1, cstarB = COLS - 1;
    if (kk > 0 && needA != eqA)         cstarA = tie_cut(ubA, TA, needA);
    if (kk > 0 && hasB && needB != eqB) cstarB = tie_cut(ubB, TB, needB);

    // ---- Compose + NT stores, straight from registers. No barriers. ----
    #pragma unroll
    for (int i = 0; i < NV; ++i) {
        const unsigned cb = (unsigned)(i * TPB + tid) * 4u;
        const unsigned u0 = ubA[i].x, u1 = ubA[i].y, u2 = ubA[i].z, u3 = ubA[i].w;
        fvec4 o;
        o.x = (u0 > TA || (u0 == TA && (cb + 0) <= cstarA)) ? __uint_as_float(u0) : 0.f;
        o.y = (u1 > TA || (u1 == TA && (cb + 1) <= cstarA)) ? __uint_as_float(u1) : 0.f;
        o.z = (u2 > TA || (u2 == TA && (cb + 2) <= cstarA)) ? __uint_as_float(u2) : 0.f;
        o.w = (u3 > TA || (u3 == TA && (cb + 3) <= cstarA)) ? __uint_as_float(u3) : 0.f;
        __builtin_nontemporal_store(o, &orA[i * TPB + tid]);
    }
    if (hasB) {
        #pragma unroll
        for (int i = 0; i < NV; ++i) {
            const unsigned cb = (unsigned)(i * TPB + tid) * 4u;
            const unsigned u0 = ubB[i].x, u1 = ubB[i].y, u2 = ubB[i].z, u3 = ubB[i].w;
            fvec4 o;
            o.x = (u0 > TB || (u0 == TB && (cb + 0) <= cstarB)) ? __uint_as_float(u0) : 0.f;
            o.y = (u1 > TB || (u1 == TB && (cb + 1) <= cstarB)) ? __uint_as_float(u1) : 0.f;
            o.z = (u2 > TB || (u2 == TB && (cb + 2) <= cstarB)) ? __uint_as_float(u2) : 0.f;
            o.w = (u3 > TB || (u3 == TB && (cb + 3) <= cstarB)) ? __uint_as_float(u3) : 0.f;
            __builtin_nontemporal_store(o, &orB[i * TPB + tid]);
        }
    }
}

extern "C" void kernel_launch(void* const* d_in, const int* in_sizes, int n_in,
                              void* d_out, int out_size, void* d_ws, size_t ws_size,
                              hipStream_t stream)
{
    const float* x   = (const float*)d_in[0];
    const int*   kp  = (const int*)d_in[1];
    float*       out = (float*)d_out;
    int rows = in_sizes[0] / COLS;               // 4096 for the reference shape
    int grid = (rows + RPB - 1) / RPB;
    topk_abs_kernel<<<grid, TPB, 0, stream>>>(x, kp, out, rows);
}

// Round 17
// 86.747 us; speedup vs baseline: 1.0839x; 1.0839x over previous
//
#include <hip/hip_runtime.h>

#define COLS 16384
#define TPB  512
#define NV   8                   // vec4 per thread (8*512*4 = 16384 cols)
#define NW   (TPB / 64)          // 8 waves
#define NBIN 4096
#define CHK  (NBIN / TPB)        // 8 bins per thread in the scan
#define SH1  12

typedef unsigned uvec4 __attribute__((ext_vector_type(4)));
typedef float    fvec4 __attribute__((ext_vector_type(4)));

__global__ __launch_bounds__(TPB, 8) void topk_abs_kernel(
    const float* __restrict__ x, const int* __restrict__ kp,
    float* __restrict__ out)
{
    __shared__ int      hist[NBIN];     // 16 KB (fallback radix reuses [0,256))
    __shared__ int      wsum[NW];
    __shared__ unsigned s_cnt, s_max, s_total;
    __shared__ int      s_bin, s_G, s_eq;

    const int tid = threadIdx.x, lane = tid & 63, wid = tid >> 6;
    const int row = blockIdx.x;
    const int kin = kp[0];
    const unsigned kk = (unsigned)(kin < 0 ? 0 : (kin > COLS ? COLS : kin));

    const uvec4* __restrict__ xr  = (const uvec4*)(x + (size_t)row * COLS);
    fvec4* __restrict__       or4 = (fvec4*)(out + (size_t)row * COLS);

    // ---- PLAIN cached loads (L3 serves ~50% across graph replays — r12 vs r7
    // A/B: FETCH 131 vs 262 MB). NT stores keep the streaming output from
    // evicting the cached input. One row per block: 32 data VGPRs -> fits the
    // 64-VGPR cap of launch_bounds(512,8) -> 4 blocks/CU (r13's spill was the
    // 2-row variant's 64 live data VGPRs). ----
    uvec4 ub[NV];
    #pragma unroll
    for (int i = 0; i < NV; ++i) ub[i] = xr[i * TPB + tid];
    #pragma unroll
    for (int j = 0; j < CHK; ++j) hist[tid + j * TPB] = 0;
    __syncthreads();

    const unsigned T0 = 0x3FE66666u;    // bits(1.8f)

    // ---- Pass 1: |x| mask + fixed-bin histogram (u-T0)>>12, clamp 4095.
    // Bins cover |x| in [1.8, 7.2); N(0,1) tail ~7.2% -> ~1180 counts. ----
    #pragma unroll
    for (int i = 0; i < NV; ++i) {
        uvec4 t = ub[i] & 0x7FFFFFFFu;
        ub[i] = t;
        #define H1(u) { if ((u) >= T0) { unsigned b = ((u) - T0) >> SH1; \
                        b = b < (NBIN - 1) ? b : (NBIN - 1); atomicAdd(&hist[b], 1); } }
        H1(t.x) H1(t.y) H1(t.z) H1(t.w)
        #undef H1
    }
    __syncthreads();

    // ---- Descending suffix-scan over hist + crossing pick ----
    auto scan_pick = [&](int rank) {
        const int c  = (TPB - 1) - tid;          // tid 0 owns the TOP chunk
        const int b0 = c * CHK;
        int S = 0;
        #pragma unroll
        for (int j = 0; j < CHK; ++j) S += hist[b0 + j];
        int P = S;
        #pragma unroll
        for (int d = 1; d < 64; d <<= 1) { int t = __shfl_up(P, d); if (lane >= d) P += t; }
        if (lane == 63) wsum[wid] = P;
        __syncthreads();
        for (int w = 0; w < wid; ++w) P += wsum[w];
        const int above = P - S;                 // count strictly above this chunk
        if (P >= rank && above < rank) {         // unique crossing chunk
            int cum = above;
            #pragma unroll
            for (int j = CHK - 1; j >= 0; --j) {
                int h = hist[b0 + j], prev = cum;
                cum += h;
                if (cum >= rank && prev < rank) { s_bin = b0 + j; s_G = prev; s_eq = h; }
            }
        }
        if (tid == TPB - 1) s_total = (unsigned)P;   // chunk 0 inclusive = total
        __syncthreads();
    };

    unsigned T = 0xFFFFFFFFu;                    // kk==0 -> accept nothing
    int need = 0, eq = 0;
    if (kk > 0) {
        scan_pick((int)kk);
        const unsigned cnt = s_total;
        const int B1 = s_bin, G1 = s_G, E1 = s_eq;   // valid iff cnt >= kk
        bool handled = false;
        if (cnt == kk) { T = T0; need = 0; eq = 0; handled = true; }
        else if (cnt > kk && B1 < NBIN - 1) {
            if (G1 + E1 == (int)kk) {
                // rank boundary == bin floor: accept all >= bin base (~85%)
                T = T0 + ((unsigned)B1 << SH1); need = 0; eq = 0; handled = true;
            } else {
                // ---- Pass 2 (~15%): exact select inside bin B1 (4096 keys) ----
                const unsigned A1 = T0 + ((unsigned)B1 << SH1);
                const int r1 = (int)kk - G1;
                #pragma unroll
                for (int j = 0; j < CHK; ++j) hist[tid + j * TPB] = 0;
                __syncthreads();
                #pragma unroll
                for (int i = 0; i < NV; ++i) {
                    #define H2(u) { unsigned d = (u) - A1; if (d < (unsigned)NBIN) atomicAdd(&hist[d], 1); }
                    H2(ub[i].x) H2(ub[i].y) H2(ub[i].z) H2(ub[i].w)
                    #undef H2
                }
                __syncthreads();
                scan_pick(r1);
                T = A1 + (unsigned)s_bin; need = r1 - s_G; eq = s_eq;
                handled = true;
            }
        }
        if (!handled) {
            // ---- Rare fallback (cnt < kk, or boundary in clamp bin):
            // bisection + adaptive 256-bin radix from registers. ----
            if (tid == 0) s_max = 0u;
            __syncthreads();
            unsigned lmax = 0u;
            #pragma unroll
            for (int i = 0; i < NV; ++i)
                lmax = max(lmax, max(max(ub[i].x, ub[i].y), max(ub[i].z, ub[i].w)));
            #pragma unroll
            for (int d = 32; d; d >>= 1) lmax = max(lmax, (unsigned)__shfl_xor((int)lmax, d));
            if (lane == 0) atomicMax(&s_max, lmax);
            __syncthreads();
            const unsigned smax = s_max;

            auto count_ge = [&](unsigned Tq) -> unsigned {
                __syncthreads();
                if (tid == 0) s_cnt = 0;
                __syncthreads();
                int c = 0;
                #pragma unroll
                for (int i = 0; i < NV; ++i)
                    c += (ub[i].x >= Tq) + (ub[i].y >= Tq) + (ub[i].z >= Tq) + (ub[i].w >= Tq);
                #pragma unroll
                for (int d = 32; d; d >>= 1) c += __shfl_xor(c, d);
                if (lane == 0) atomicAdd(&s_cnt, (unsigned)c);
                __syncthreads();
                return s_cnt;
            };

            unsigned T0f = T0, cntf = s_total;
            if (cntf < kk) {                     // lower the threshold exactly
                unsigned lo = 0u, hi = T0;
                while (hi - lo > 1u) {
                    unsigned mid = lo + ((hi - lo) >> 1);
                    if (count_ge(mid) >= kk) lo = mid; else hi = mid;
                }
                T0f = lo;
                cntf = count_ge(T0f);
            }
            if (cntf == kk)       { T = T0f; need = 0; eq = 0; }
            else if (smax == T0f) { T = T0f; eq = (int)cntf; need = (int)kk; }
            else {
                const unsigned range = smax - T0f;
                const int topbit = 31 - __clz(range);
                int sh = topbit - 7; if (sh < 0) sh = 0;
                unsigned A = T0f;
                unsigned W = (topbit >= 31) ? 0xFFFFFFFFu : (1u << (topbit + 1));
                int r = (int)kk;
                for (;;) {
                    if (tid < 256) hist[tid] = 0;
                    __syncthreads();
                    #pragma unroll
                    for (int i = 0; i < NV; ++i) {
                        #define HR(u) { if ((u) >= A && ((u) - A) < W) atomicAdd(&hist[((u) - A) >> sh], 1); }
                        HR(ub[i].x) HR(ub[i].y) HR(ub[i].z) HR(ub[i].w)
                        #undef HR
                    }
                    __syncthreads();
                    int bin = 0, val = 0, s = 0;
                    if (tid < 256) {
                        bin = 255 - tid;
                        val = hist[bin];
                        s = val;
                        #pragma unroll
                        for (int d = 1; d < 64; d <<= 1) { int t = __shfl_up(s, d); if (lane >= d) s += t; }
                        if (lane == 63) wsum[wid] = s;
                    }
                    __syncthreads();
                    if (tid < 256) {
                        for (int w = 0; w < wid && w < 4; ++w) s += wsum[w];
                        if (s >= r && (s - val) < r) { s_bin = bin; s_G = s - val; if (sh == 0) s_eq = val; }
                    }
                    __syncthreads();
                    A += ((unsigned)s_bin) << sh;
                    W = 1u << sh;
                    r -= s_G;
                    if (sh == 0) break;
                    sh = (sh >= 8) ? sh - 8 : 0;
                    __syncthreads();
                }
                T = A; need = r; eq = s_eq;
            }
        }
    }

    // ---- Boundary tie (need != eq, rare): among u==T accept the `need`
    // lowest columns; bisect the cutoff column with register-direct counts. ----
    unsigned cstar = COLS - 1;                   // default: accept all equals
    if (kk > 0 && need != eq) {
        unsigned loC = 0, hiC = COLS - 1;
        while (loC < hiC) {
            unsigned mid = (loC + hiC) >> 1;
            __syncthreads();
            if (tid == 0) s_cnt = 0;
            __syncthreads();
            int c = 0;
            #pragma unroll
            for (int i = 0; i < NV; ++i) {
                const unsigned cb = (unsigned)(i * TPB + tid) * 4u;
                c += (ub[i].x == T && (cb + 0) <= mid);
                c += (ub[i].y == T && (cb + 1) <= mid);
                c += (ub[i].z == T && (cb + 2) <= mid);
                c += (ub[i].w == T && (cb + 3) <= mid);
            }
            #pragma unroll
            for (int d = 32; d; d >>= 1) c += __shfl_xor(c, d);
            if (lane == 0) atomicAdd(&s_cnt, (unsigned)c);
            __syncthreads();
            if (s_cnt >= (unsigned)need) hiC = mid; else loC = mid + 1;
        }
        cstar = loC;
    }

    // ---- Compose + non-temporal write, straight from registers. ----
    #pragma unroll
    for (int i = 0; i < NV; ++i) {
        const unsigned cb = (unsigned)(i * TPB + tid) * 4u;
        const unsigned u0 = ub[i].x, u1 = ub[i].y, u2 = ub[i].z, u3 = ub[i].w;
        fvec4 o;
        o.x = (u0 > T || (u0 == T && (cb + 0) <= cstar)) ? __uint_as_float(u0) : 0.f;
        o.y = (u1 > T || (u1 == T && (cb + 1) <= cstar)) ? __uint_as_float(u1) : 0.f;
        o.z = (u2 > T || (u2 == T && (cb + 2) <= cstar)) ? __uint_as_float(u2) : 0.f;
        o.w = (u3 > T || (u3 == T && (cb + 3) <= cstar)) ? __uint_as_float(u3) : 0.f;
        __builtin_nontemporal_store(o, &or4[i * TPB + tid]);
    }
}

extern "C" void kernel_launch(void* const* d_in, const int* in_sizes, int n_in,
                              void* d_out, int out_size, void* d_ws, size_t ws_size,
                              hipStream_t stream)
{
    const float* x   = (const float*)d_in[0];
    const int*   kp  = (const int*)d_in[1];
    float*       out = (float*)d_out;
    int rows = in_sizes[0] / COLS;               // 4096 for the reference shape
    topk_abs_kernel<<<rows, TPB, 0, stream>>>(x, kp, out);
}

// Round 18
// 76.046 us; speedup vs baseline: 1.2364x; 1.1407x over previous
//
#include <hip/hip_runtime.h>

#define COLS 16384
#define TPB  1024
#define NV   4                   // vec4 per thread (4*1024*4 = 16384 cols)
#define NW   (TPB / 64)          // 16 waves
#define NBIN 4096
#define CHK  (NBIN / TPB)        // 4 bins per thread in the scan
#define SH1  12

typedef unsigned uvec4 __attribute__((ext_vector_type(4)));
typedef float    fvec4 __attribute__((ext_vector_type(4)));

__global__ __launch_bounds__(TPB, 8) void topk_abs_kernel(
    const float* __restrict__ x, const int* __restrict__ kp,
    float* __restrict__ out)
{
    __shared__ int      hist[NBIN];     // 16 KB (fallback radix reuses [0,256))
    __shared__ int      wsum[NW];
    __shared__ unsigned s_cnt, s_max, s_total;
    __shared__ int      s_bin, s_G, s_eq;

    const int tid = threadIdx.x, lane = tid & 63, wid = tid >> 6;
    const int row = blockIdx.x;
    const int kin = kp[0];
    const unsigned kk = (unsigned)(kin < 0 ? 0 : (kin > COLS ? COLS : kin));

    const uvec4* __restrict__ xr  = (const uvec4*)(x + (size_t)row * COLS);
    fvec4* __restrict__       or4 = (fvec4*)(out + (size_t)row * COLS);

    // ---- PLAIN cached loads (L3 serves ~50% across graph replays — r12 vs r7
    // A/B: FETCH 131 vs 262 MB). NT stores keep the streaming output from
    // evicting the cached input. One row per block (r12's RPB=2 bundled with
    // the plain-load win; r9/r11 showed the RPB structure itself is null). ----
    uvec4 ub[NV];
    #pragma unroll
    for (int i = 0; i < NV; ++i) ub[i] = xr[i * TPB + tid];
    #pragma unroll
    for (int j = 0; j < CHK; ++j) hist[tid + j * TPB] = 0;
    __syncthreads();

    const unsigned T0 = 0x3FE66666u;    // bits(1.8f)

    // ---- Pass 1: |x| mask + fixed-bin histogram (u-T0)>>12, clamp 4095.
    // Bins cover |x| in [1.8, 7.2); N(0,1) tail ~7.2% -> ~1180 counts. ----
    #pragma unroll
    for (int i = 0; i < NV; ++i) {
        uvec4 t = ub[i] & 0x7FFFFFFFu;
        ub[i] = t;
        #define H1(u) { if ((u) >= T0) { unsigned b = ((u) - T0) >> SH1; \
                        b = b < (NBIN - 1) ? b : (NBIN - 1); atomicAdd(&hist[b], 1); } }
        H1(t.x) H1(t.y) H1(t.z) H1(t.w)
        #undef H1
    }
    __syncthreads();

    // ---- Descending suffix-scan over hist + crossing pick ----
    auto scan_pick = [&](int rank) {
        const int c  = (TPB - 1) - tid;          // tid 0 owns the TOP chunk
        const int b0 = c * CHK;
        int S = 0;
        #pragma unroll
        for (int j = 0; j < CHK; ++j) S += hist[b0 + j];
        int P = S;
        #pragma unroll
        for (int d = 1; d < 64; d <<= 1) { int t = __shfl_up(P, d); if (lane >= d) P += t; }
        if (lane == 63) wsum[wid] = P;
        __syncthreads();
        for (int w = 0; w < wid; ++w) P += wsum[w];
        const int above = P - S;                 // count strictly above this chunk
        if (P >= rank && above < rank) {         // unique crossing chunk
            int cum = above;
            #pragma unroll
            for (int j = CHK - 1; j >= 0; --j) {
                int h = hist[b0 + j], prev = cum;
                cum += h;
                if (cum >= rank && prev < rank) { s_bin = b0 + j; s_G = prev; s_eq = h; }
            }
        }
        if (tid == TPB - 1) s_total = (unsigned)P;   // chunk 0 inclusive = total
        __syncthreads();
    };

    unsigned T = 0xFFFFFFFFu;                    // kk==0 -> accept nothing
    int need = 0, eq = 0;
    if (kk > 0) {
        scan_pick((int)kk);
        const unsigned cnt = s_total;
        const int B1 = s_bin, G1 = s_G, E1 = s_eq;   // valid iff cnt >= kk
        bool handled = false;
        if (cnt == kk) { T = T0; need = 0; eq = 0; handled = true; }
        else if (cnt > kk && B1 < NBIN - 1) {
            if (G1 + E1 == (int)kk) {
                // rank boundary == bin floor: accept all >= bin base (~85%)
                T = T0 + ((unsigned)B1 << SH1); need = 0; eq = 0; handled = true;
            } else {
                // ---- Pass 2 (~15%): exact select inside bin B1 (4096 keys) ----
                const unsigned A1 = T0 + ((unsigned)B1 << SH1);
                const int r1 = (int)kk - G1;
                #pragma unroll
                for (int j = 0; j < CHK; ++j) hist[tid + j * TPB] = 0;
                __syncthreads();
                #pragma unroll
                for (int i = 0; i < NV; ++i) {
                    #define H2(u) { unsigned d = (u) - A1; if (d < (unsigned)NBIN) atomicAdd(&hist[d], 1); }
                    H2(ub[i].x) H2(ub[i].y) H2(ub[i].z) H2(ub[i].w)
                    #undef H2
                }
                __syncthreads();
                scan_pick(r1);
                T = A1 + (unsigned)s_bin; need = r1 - s_G; eq = s_eq;
                handled = true;
            }
        }
        if (!handled) {
            // ---- Rare fallback (cnt < kk, or boundary in clamp bin):
            // bisection + adaptive 256-bin radix from registers. ----
            if (tid == 0) s_max = 0u;
            __syncthreads();
            unsigned lmax = 0u;
            #pragma unroll
            for (int i = 0; i < NV; ++i)
                lmax = max(lmax, max(max(ub[i].x, ub[i].y), max(ub[i].z, ub[i].w)));
            #pragma unroll
            for (int d = 32; d; d >>= 1) lmax = max(lmax, (unsigned)__shfl_xor((int)lmax, d));
            if (lane == 0) atomicMax(&s_max, lmax);
            __syncthreads();
            const unsigned smax = s_max;

            auto count_ge = [&](unsigned Tq) -> unsigned {
                __syncthreads();
                if (tid == 0) s_cnt = 0;
                __syncthreads();
                int c = 0;
                #pragma unroll
                for (int i = 0; i < NV; ++i)
                    c += (ub[i].x >= Tq) + (ub[i].y >= Tq) + (ub[i].z >= Tq) + (ub[i].w >= Tq);
                #pragma unroll
                for (int d = 32; d; d >>= 1) c += __shfl_xor(c, d);
                if (lane == 0) atomicAdd(&s_cnt, (unsigned)c);
                __syncthreads();
                return s_cnt;
            };

            unsigned T0f = T0, cntf = s_total;
            if (cntf < kk) {                     // lower the threshold exactly
                unsigned lo = 0u, hi = T0;
                while (hi - lo > 1u) {
                    unsigned mid = lo + ((hi - lo) >> 1);
                    if (count_ge(mid) >= kk) lo = mid; else hi = mid;
                }
                T0f = lo;
                cntf = count_ge(T0f);
            }
            if (cntf == kk)       { T = T0f; need = 0; eq = 0; }
            else if (smax == T0f) { T = T0f; eq = (int)cntf; need = (int)kk; }
            else {
                const unsigned range = smax - T0f;
                const int topbit = 31 - __clz(range);
                int sh = topbit - 7; if (sh < 0) sh = 0;
                unsigned A = T0f;
                unsigned W = (topbit >= 31) ? 0xFFFFFFFFu : (1u << (topbit + 1));
                int r = (int)kk;
                for (;;) {
                    if (tid < 256) hist[tid] = 0;
                    __syncthreads();
                    #pragma unroll
                    for (int i = 0; i < NV; ++i) {
                        #define HR(u) { if ((u) >= A && ((u) - A) < W) atomicAdd(&hist[((u) - A) >> sh], 1); }
                        HR(ub[i].x) HR(ub[i].y) HR(ub[i].z) HR(ub[i].w)
                        #undef HR
                    }
                    __syncthreads();
                    int bin = 0, val = 0, s = 0;
                    if (tid < 256) {
                        bin = 255 - tid;
                        val = hist[bin];
                        s = val;
                        #pragma unroll
                        for (int d = 1; d < 64; d <<= 1) { int t = __shfl_up(s, d); if (lane >= d) s += t; }
                        if (lane == 63) wsum[wid] = s;
                    }
                    __syncthreads();
                    if (tid < 256) {
                        for (int w = 0; w < wid; ++w) s += wsum[w];
                        if (s >= r && (s - val) < r) { s_bin = bin; s_G = s - val; if (sh == 0) s_eq = val; }
                    }
                    __syncthreads();
                    A += ((unsigned)s_bin) << sh;
                    W = 1u << sh;
                    r -= s_G;
                    if (sh == 0) break;
                    sh = (sh >= 8) ? sh - 8 : 0;
                    __syncthreads();
                }
                T = A; need = r; eq = s_eq;
            }
        }
    }

    // ---- Boundary tie (need != eq, rare): among u==T accept the `need`
    // lowest columns; bisect the cutoff column with register-direct counts. ----
    unsigned cstar = COLS - 1;                   // default: accept all equals
    if (kk > 0 && need != eq) {
        unsigned loC = 0, hiC = COLS - 1;
        while (loC < hiC) {
            unsigned mid = (loC + hiC) >> 1;
            __syncthreads();
            if (tid == 0) s_cnt = 0;
            __syncthreads();
            int c = 0;
            #pragma unroll
            for (int i = 0; i < NV; ++i) {
                const unsigned cb = (unsigned)(i * TPB + tid) * 4u;
                c += (ub[i].x == T && (cb + 0) <= mid);
                c += (ub[i].y == T && (cb + 1) <= mid);
                c += (ub[i].z == T && (cb + 2) <= mid);
                c += (ub[i].w == T && (cb + 3) <= mid);
            }
            #pragma unroll
            for (int d = 32; d; d >>= 1) c += __shfl_xor(c, d);
            if (lane == 0) atomicAdd(&s_cnt, (unsigned)c);
            __syncthreads();
            if (s_cnt >= (unsigned)need) hiC = mid; else loC = mid + 1;
        }
        cstar = loC;
    }

    // ---- Compose + non-temporal write, straight from registers. ----
    #pragma unroll
    for (int i = 0; i < NV; ++i) {
        const unsigned cb = (unsigned)(i * TPB + tid) * 4u;
        const unsigned u0 = ub[i].x, u1 = ub[i].y, u2 = ub[i].z, u3 = ub[i].w;
        fvec4 o;
        o.x = (u0 > T || (u0 == T && (cb + 0) <= cstar)) ? __uint_as_float(u0) : 0.f;
        o.y = (u1 > T || (u1 == T && (cb + 1) <= cstar)) ? __uint_as_float(u1) : 0.f;
        o.z = (u2 > T || (u2 == T && (cb + 2) <= cstar)) ? __uint_as_float(u2) : 0.f;
        o.w = (u3 > T || (u3 == T && (cb + 3) <= cstar)) ? __uint_as_float(u3) : 0.f;
        __builtin_nontemporal_store(o, &or4[i * TPB + tid]);
    }
}

extern "C" void kernel_launch(void* const* d_in, const int* in_sizes, int n_in,
                              void* d_out, int out_size, void* d_ws, size_t ws_size,
                              hipStream_t stream)
{
    const float* x   = (const float*)d_in[0];
    const int*   kp  = (const int*)d_in[1];
    float*       out = (float*)d_out;
    int rows = in_sizes[0] / COLS;               // 4096 for the reference shape
    topk_abs_kernel<<<rows, TPB, 0, stream>>>(x, kp, out);
}